// Round 8
// baseline (1848.436 us; speedup 1.0000x reference)
//
#include <hip/hip_runtime.h>
#include <math.h>

#define B_ 30
#define S_ 1024
#define D_ 128
#define ET_ 128
#define H_ 4
#define DK_ 32
#define NH_ 128
#define NPOS (B_*S_)   // 30720

// workspace float offsets (total 27,532,800 floats = 110.1 MB)
#define OFF_TE   0L
#define OFF_Q    3932160L
#define OFF_K    7864320L
#define OFF_CTX  11796480L
#define OFF_XS   0L          // aliases TE (dead after q/k proj)
#define OFF_GIF  3932160L    // aliases Q,K + head of CTX (dead after Wo proj)
#define OFF_GIB  15728640L   // aliases tail of CTX
#define OFF_HF   27525120L
#define OFF_HB   27528960L

typedef __attribute__((ext_vector_type(4))) short short4v;
typedef __attribute__((ext_vector_type(8))) short short8v;
typedef __attribute__((ext_vector_type(4))) float f32x4;

__device__ __forceinline__ short f2bf(float x) {
    unsigned u = __builtin_bit_cast(unsigned, x);
    unsigned r = (u + 0x7FFFu + ((u >> 16) & 1u)) >> 16;
    return (short)r;
}
__device__ __forceinline__ float bf2f(short s) {
    unsigned u = ((unsigned)(unsigned short)s) << 16;
    return __builtin_bit_cast(float, u);
}

__device__ __forceinline__ short8v pack8(const float4 a, const float4 b) {
    short8v v;
    v[0]=f2bf(a.x); v[1]=f2bf(a.y); v[2]=f2bf(a.z); v[3]=f2bf(a.w);
    v[4]=f2bf(b.x); v[5]=f2bf(b.y); v[6]=f2bf(b.z); v[7]=f2bf(b.w);
    return v;
}

// fast transcendentals (saturating-safe; GRU is a contraction so ~ulp-level
// per-step error cannot accumulate)
__device__ __forceinline__ float fsigmoid(float x) {
    return 1.f / (1.f + __expf(-x));
}
__device__ __forceinline__ float ftanh(float x) {
    return 1.f - 2.f / (__expf(2.f * x) + 1.f);
}

// ---------------------------------------------------------------- time embed
__global__ __launch_bounds__(256) void time_embed_kernel(
    const float* __restrict__ ts, const float* __restrict__ w_lin,
    const float* __restrict__ b_lin, const float* __restrict__ w_per,
    const float* __restrict__ b_per, float* __restrict__ te)
{
    const long idx = (long)blockIdx.x * 256 + threadIdx.x;  // NPOS*128 total
    const int pos = (int)(idx >> 7);
    const int j = (int)(idx & 127);
    const float tv = ts[pos];
    float v;
    if (j == 0) v = tv * w_lin[0] + b_lin[0];
    else        v = sinf(tv * w_per[j-1] + b_per[j-1]);
    te[idx] = v;
}

// ------------------------------------------------------- generic tiled GEMM
// C[m,n] = sum_f A[m,f]*W[n,f] + bias[n]
// REMAP==0: plain. REMAP==1: write row m=b*S+s to xs row s*B+b (Wo proj).
// REMAP==2: read A row for logical m=s*B+b from (S-1-s)*B+b (backward gi).
template<int REMAP>
__global__ __launch_bounds__(256) void gemm_kernel(
    const float* __restrict__ A, const float* __restrict__ W,
    const float* __restrict__ bias, float* __restrict__ C,
    int M, int N, int K)
{
    __shared__ float Wsh[128][129];
    __shared__ float Ash[64][129];
    const int t = threadIdx.x;
    const int m0 = blockIdx.x * 64;
    const int n0 = blockIdx.y * 128;
    const int e  = t & 31;
    const int rb = (t >> 5) * 8;
    float acc[8][4];
#pragma unroll
    for (int i = 0; i < 8; ++i)
#pragma unroll
        for (int j = 0; j < 4; ++j) acc[i][j] = 0.f;

    for (int k0 = 0; k0 < K; k0 += 128) {
        const int f = t & 127;
        {
            const int e0 = t >> 7;
#pragma unroll 8
            for (int i = 0; i < 64; ++i) {
                const int n = e0 + 2*i;
                Wsh[n][f] = W[(long)(n0 + n) * K + k0 + f];
            }
            const int r0 = t >> 7;
#pragma unroll 8
            for (int i = 0; i < 32; ++i) {
                const int r = r0 + 2*i;
                const int m = m0 + r;
                long src;
                if (REMAP == 2) {
                    const int s = m / B_, bb = m % B_;
                    src = (long)((S_-1-s)*B_ + bb) * K;
                } else {
                    src = (long)m * K;
                }
                Ash[r][f] = A[src + k0 + f];
            }
        }
        __syncthreads();
#pragma unroll 2
        for (int ff = 0; ff < 128; ++ff) {
            float av[8];
#pragma unroll
            for (int rr = 0; rr < 8; ++rr) av[rr] = Ash[rb+rr][ff];
#pragma unroll
            for (int cg = 0; cg < 4; ++cg) {
                const float wv = Wsh[e + 32*cg][ff];
#pragma unroll
                for (int rr = 0; rr < 8; ++rr)
                    acc[rr][cg] = fmaf(av[rr], wv, acc[rr][cg]);
            }
        }
        __syncthreads();
    }
#pragma unroll
    for (int rr = 0; rr < 8; ++rr) {
#pragma unroll
        for (int cg = 0; cg < 4; ++cg) {
            const int n = n0 + e + 32*cg;
            const int m = m0 + rb + rr;
            const float v = acc[rr][cg] + bias[n];
            if (REMAP == 1) {
                const int bb = m / S_, s = m % S_;
                C[(long)(s*B_ + bb) * N + n] = v;
            } else {
                C[(long)m * N + n] = v;
            }
        }
    }
}

// ------------------------------------------------------------ fused attention
// MFMA flash attention, p-minus-one formulation (see round-3 notes).
#define SCALE_LOG2 (0.17677669529663687f * 1.4426950408889634f)

__global__ __launch_bounds__(256) void attn_kernel(
    const float* __restrict__ qbuf, const float* __restrict__ kbuf,
    const float* __restrict__ x, float* __restrict__ ctx)
{
    const int qt = blockIdx.x;   // 0..15
    const int h  = blockIdx.y;   // 0..3
    const int b  = blockIdx.z;   // 0..29
    const int q0 = qt * 64;
    const int t  = threadIdx.x;
    const int w    = t >> 6;
    const int lane = t & 63;
    const int l15  = lane & 15;
    const int lg   = lane >> 4;

    __shared__ short K_lds[64][40];     //  5120 B
    __shared__ short XT_lds[128][68];   // 17408 B, XT[d][key]
    __shared__ short P_lds[4][16][88];  // 11264 B, per-wave P' rows

    // Q fragment (scale*log2e folded in), held in registers
    short8v qf;
    {
        const float* qp = qbuf + ((long)(b*S_ + q0 + 16*w + l15))*ET_ + h*DK_ + 8*lg;
        float4 a = *(const float4*)qp;
        float4 c = *(const float4*)(qp + 4);
        a.x*=SCALE_LOG2; a.y*=SCALE_LOG2; a.z*=SCALE_LOG2; a.w*=SCALE_LOG2;
        c.x*=SCALE_LOG2; c.y*=SCALE_LOG2; c.z*=SCALE_LOG2; c.w*=SCALE_LOG2;
        qf = pack8(a, c);
    }

    short8v ones;
#pragma unroll
    for (int i = 0; i < 8; ++i) ones[i] = (short)0x3F80;  // bf16 1.0

    f32x4 acc[8];
#pragma unroll
    for (int i = 0; i < 8; ++i) acc[i] = (f32x4){0.f,0.f,0.f,0.f};
    float lsum = 0.f;
    const f32x4 zf = (f32x4){0.f,0.f,0.f,0.f};

    for (int kt = 0; kt < 16; ++kt) {
        const int key0 = kt * 64;
        // ---- stage K tile (64 keys x 32 dk, bf16, rows padded to 40)
        {
            const int key = t >> 2, c8 = (t & 3) * 8;
            const float* kp = kbuf + ((long)(b*S_ + key0 + key))*ET_ + h*DK_ + c8;
            float4 a = *(const float4*)kp;
            float4 c = *(const float4*)(kp + 4);
            *(short8v*)&K_lds[key][c8] = pack8(a, c);
        }
        // ---- stage X tile transposed: XT[d][key], key-pairs packed as u32
        {
            const int k2 = t & 31;       // key pair 2*k2, 2*k2+1
            const int dg = t >> 5;       // d range [16*dg, 16*dg+16)
            const float* xp0 = x + ((long)(b*S_ + key0 + 2*k2))*D_ + 16*dg;
            const float* xp1 = xp0 + D_;
            float v0[16], v1[16];
#pragma unroll
            for (int j4 = 0; j4 < 4; ++j4) {
                float4 a = ((const float4*)xp0)[j4];
                float4 c = ((const float4*)xp1)[j4];
                v0[4*j4+0]=a.x; v0[4*j4+1]=a.y; v0[4*j4+2]=a.z; v0[4*j4+3]=a.w;
                v1[4*j4+0]=c.x; v1[4*j4+1]=c.y; v1[4*j4+2]=c.z; v1[4*j4+3]=c.w;
            }
#pragma unroll
            for (int j = 0; j < 16; ++j) {
                unsigned u = (unsigned)(unsigned short)f2bf(v0[j])
                           | ((unsigned)(unsigned short)f2bf(v1[j]) << 16);
                *(unsigned*)&XT_lds[16*dg + j][2*k2] = u;
            }
        }
        __syncthreads();

        // ---- QK^T (swapped): sc[f] = K_frag(16 keys) x Q  -> S^T
        f32x4 sc[4];
#pragma unroll
        for (int f = 0; f < 4; ++f) {
            short8v kf = *(const short8v*)&K_lds[16*f + l15][8*lg];
            sc[f] = __builtin_amdgcn_mfma_f32_16x16x32_bf16(kf, qf, zf, 0, 0, 0);
        }

        // ---- p = exp2(s), store p' = p-1; accumulate row-sum of p
        float pw[4][4];
        float ps = 0.f;
#pragma unroll
        for (int f = 0; f < 4; ++f)
#pragma unroll
            for (int r = 0; r < 4; ++r) {
                const float p = exp2f(sc[f][r]);
                ps += p;
                pw[f][r] = p - 1.f;
            }
        ps += __shfl_xor(ps, 16);
        ps += __shfl_xor(ps, 32);
        lsum += ps;   // per-lane stat for q-row l15 (uniform across lg lanes)

        // ---- write P' to per-wave LDS as bf16 (pairs of adjacent keys)
#pragma unroll
        for (int f = 0; f < 4; ++f) {
            unsigned lo = (unsigned)(unsigned short)f2bf(pw[f][0])
                        | ((unsigned)(unsigned short)f2bf(pw[f][1]) << 16);
            unsigned hi = (unsigned)(unsigned short)f2bf(pw[f][2])
                        | ((unsigned)(unsigned short)f2bf(pw[f][3]) << 16);
            *(unsigned*)&P_lds[w][l15][16*f + 4*lg]     = lo;
            *(unsigned*)&P_lds[w][l15][16*f + 4*lg + 2] = hi;
        }

        // ---- PV: acc[dq] += (ones + P') x X   (two MFMAs per B-frag)
#pragma unroll
        for (int kb = 0; kb < 2; ++kb) {
            short8v pa = *(const short8v*)&P_lds[w][l15][32*kb + 8*lg];
#pragma unroll
            for (int dq = 0; dq < 8; ++dq) {
                const short* xr = &XT_lds[16*dq + l15][32*kb + 8*lg];
                short4v lo = *(const short4v*)xr;        // 8B-aligned ds_read_b64
                short4v hi = *(const short4v*)(xr + 4);
                short8v xb = __builtin_shufflevector(lo, hi, 0,1,2,3,4,5,6,7);
                acc[dq] = __builtin_amdgcn_mfma_f32_16x16x32_bf16(ones, xb, acc[dq], 0, 0, 0);
                acc[dq] = __builtin_amdgcn_mfma_f32_16x16x32_bf16(pa,   xb, acc[dq], 0, 0, 0);
            }
        }
        __syncthreads();
    }

    // ---- epilogue: normalize by 1/lsum, store ctx[b,s,h,d]
    const float inv = 1.f / lsum;
#pragma unroll
    for (int r = 0; r < 4; ++r) {
        const float ir = __shfl(inv, (lane & 48) | (4*lg + r));
        const long base = ((long)(b*S_ + q0 + 16*w + 4*lg + r)*H_ + h)*D_ + l15;
#pragma unroll
        for (int d = 0; d < 8; ++d)
            ctx[base + (long)d*16] = acc[d][r] * ir;
    }
}

// ----------------------------------------------------------------- GRU scan
// 60 blocks: dir (0=f,1=b) x batch. 512 threads = 8 waves.
// Wave w OWNS h rows [16w,16w+16): its 3 Whh row-tiles are gate rows
// {16w, 128+16w, 256+16w}, so after its MFMAs the lane holds ghr/ghz/ghn for
// its own h indices j0=16w+4lg..+3 IN REGISTERS. Gate math replicated in all
// lanes; l15==0 lanes publish new h (bf16, 8B) into double-buffered hbf ->
// ONE barrier per step.
// REGISTER BUDGET (R7 post-mortem): live state ~190 VGPR (96 weight frags +
// 16 hfrag + 36 gi/prefetch/bias + chains). __launch_bounds__(512,2) capped
// the allocator at 128 -> weight frags spilled to scratch every step
// (WRITE_SIZE 30->1590 KB, 2x slowdown). Grid is 60 blocks on 256 CUs, so
// >1 block/CU never happens anyway: use (512,1) -> 256-VGPR cap, no spill.
__global__ __launch_bounds__(512, 1) void gru_kernel(
    const float* __restrict__ gi_f, const float* __restrict__ gi_b,
    const float* __restrict__ Whh_f, const float* __restrict__ bhh_f,
    const float* __restrict__ Whh_b, const float* __restrict__ bhh_b,
    float* __restrict__ hf, float* __restrict__ hb)
{
    const int bid = blockIdx.x;
    const int dir = bid / B_;
    const int b   = bid % B_;
    const float* gi  = dir ? gi_b  : gi_f;
    const float* Whh = dir ? Whh_b : Whh_f;
    const float* bhh = dir ? bhh_b : bhh_f;
    float* hout      = dir ? hb    : hf;
    const int t    = threadIdx.x;        // 0..511
    const int w    = t >> 6;             // wave 0..7 -> h rows [16w,16w+16)
    const int lane = t & 63;
    const int l15  = lane & 15;
    const int lg   = lane >> 4;
    const int j0   = 16*w + 4*lg;        // this lane's 4 h indices

    // Whh fragments: tile rt covers gate rows 128*rt + [16w, 16w+16)
    short8v wa_hi[3][4], wa_lo[3][4];
#pragma unroll
    for (int rt = 0; rt < 3; ++rt) {
        const int row = 128*rt + 16*w + l15;
#pragma unroll
        for (int kf = 0; kf < 4; ++kf) {
            const float* wp = Whh + (long)row*128 + 32*kf + 8*lg;
            float4 a = *(const float4*)wp;
            float4 c = *(const float4*)(wp + 4);
            short8v hi8 = pack8(a, c);
            float rv[8] = {a.x,a.y,a.z,a.w,c.x,c.y,c.z,c.w};
            short8v lo8;
#pragma unroll
            for (int e = 0; e < 8; ++e)
                lo8[e] = f2bf(rv[e] - bf2f(hi8[e]));
            wa_hi[rt][kf] = hi8;
            wa_lo[rt][kf] = lo8;
        }
    }

    // biases for this lane's rows
    const f32x4 br = *(const f32x4*)(bhh + j0);
    const f32x4 bz = *(const f32x4*)(bhh + 128 + j0);
    const f32x4 bn = *(const f32x4*)(bhh + 256 + j0);

    __shared__ __align__(16) short hbf[2][128];
    if (t < 64) ((unsigned*)&hbf[0][0])[t] = 0;   // zero buf0 (h0 = 0)
    __syncthreads();

    f32x4 hcur = (f32x4){0.f,0.f,0.f,0.f};        // f32 recurrence state

    // gi for step 0
    const float* g0 = gi + (long)b * 384;
    f32x4 gr = *(const f32x4*)(g0 + j0);
    f32x4 gz = *(const f32x4*)(g0 + 128 + j0);
    f32x4 gn = *(const f32x4*)(g0 + 256 + j0);

    for (int s = 0; s < S_; ++s) {
        const int cur = s & 1, nxt = cur ^ 1;

        // B-fragments: h broadcast (same 16B chunk for all l15)
        short8v hfrag[4];
#pragma unroll
        for (int kf = 0; kf < 4; ++kf)
            hfrag[kf] = *(const short8v*)&hbf[cur][32*kf + 8*lg];

        // prefetch next step's gi (latency hides under the MFMA phase)
        f32x4 ngr = gr, ngz = gz, ngn = gn;
        if (s + 1 < S_) {
            const float* g = gi + ((long)(s+1)*B_ + b) * 384;
            ngr = *(const f32x4*)(g + j0);
            ngz = *(const f32x4*)(g + 128 + j0);
            ngn = *(const f32x4*)(g + 256 + j0);
        }

        // gh tiles on the matrix pipe (hi/lo chains split: dep depth 4)
        f32x4 gh0, gh1, gh2;
        {
            f32x4 ah, al;
#define GH_TILE(rt, OUT) \
            ah = (f32x4){0.f,0.f,0.f,0.f}; al = (f32x4){0.f,0.f,0.f,0.f}; \
            _Pragma("unroll") \
            for (int kf = 0; kf < 4; ++kf) \
                ah = __builtin_amdgcn_mfma_f32_16x16x32_bf16(wa_hi[rt][kf], hfrag[kf], ah, 0,0,0); \
            _Pragma("unroll") \
            for (int kf = 0; kf < 4; ++kf) \
                al = __builtin_amdgcn_mfma_f32_16x16x32_bf16(wa_lo[rt][kf], hfrag[kf], al, 0,0,0); \
            OUT = ah + al;
            GH_TILE(0, gh0)
            GH_TILE(1, gh1)
            GH_TILE(2, gh2)
#undef GH_TILE
        }

        // gate math for j0..j0+3 (replicated across l15 lanes)
#pragma unroll
        for (int r = 0; r < 4; ++r) {
            const float rr = fsigmoid(gr[r] + gh0[r] + br[r]);
            const float zz = fsigmoid(gz[r] + gh1[r] + bz[r]);
            const float nn = ftanh (gn[r] + rr * (gh2[r] + bn[r]));
            hcur[r] = (1.f - zz)*nn + zz*hcur[r];
        }

        // publish new h (bf16) for next step's B-fragments
        if (l15 == 0) {
            short4v hv;
#pragma unroll
            for (int r = 0; r < 4; ++r) hv[r] = f2bf(hcur[r]);
            *(short4v*)&hbf[nxt][j0] = hv;
        }
        gr = ngr; gz = ngz; gn = ngn;
        __syncthreads();
    }

    if (l15 == 0)
        *(f32x4*)&hout[(long)b*128 + j0] = hcur;
}

// -------------------------------------------------------------- classifier
__global__ __launch_bounds__(128) void classifier_kernel(
    const float* __restrict__ hf, const float* __restrict__ hb,
    const float* __restrict__ W1, const float* __restrict__ b1,
    const float* __restrict__ W2, const float* __restrict__ b2,
    const float* __restrict__ W3, const float* __restrict__ b3,
    float* __restrict__ out)
{
    const int b = blockIdx.x;
    const int t = threadIdx.x;
    __shared__ float cin[256], a1[128], a2[64];
    cin[t]       = hf[(long)b*128 + t];
    cin[128 + t] = hb[(long)b*128 + t];
    __syncthreads();
    {
        float a = b1[t];
        for (int i = 0; i < 256; ++i) a = fmaf(W1[(long)t*256 + i], cin[i], a);
        a1[t] = a;
    }
    __syncthreads();
    if (t < 64) {
        float a = b2[t];
        for (int i = 0; i < 128; ++i) a = fmaf(W2[(long)t*128 + i], a1[i], a);
        a2[t] = a;
    }
    __syncthreads();
    if (t < 6) {
        float a = b3[t];
        for (int i = 0; i < 64; ++i) a = fmaf(W3[(long)t*64 + i], a2[i], a);
        out[(long)b*6 + t] = a;
    }
}

// ------------------------------------------------------------------- launch
extern "C" void kernel_launch(void* const* d_in, const int* in_sizes, int n_in,
                              void* d_out, int out_size, void* d_ws, size_t ws_size,
                              hipStream_t stream)
{
    const float* x     = (const float*)d_in[0];
    const float* ts    = (const float*)d_in[1];
    const float* w_lin = (const float*)d_in[2];
    const float* b_lin = (const float*)d_in[3];
    const float* w_per = (const float*)d_in[4];
    const float* b_per = (const float*)d_in[5];
    const float* Wq    = (const float*)d_in[6];
    const float* bq    = (const float*)d_in[7];
    const float* Wk    = (const float*)d_in[8];
    const float* bk    = (const float*)d_in[9];
    const float* Wo    = (const float*)d_in[10];
    const float* bo    = (const float*)d_in[11];
    const float* Wih_f = (const float*)d_in[12];
    const float* Whh_f = (const float*)d_in[13];
    const float* bih_f = (const float*)d_in[14];
    const float* bhh_f = (const float*)d_in[15];
    const float* Wih_b = (const float*)d_in[16];
    const float* Whh_b = (const float*)d_in[17];
    const float* bih_b = (const float*)d_in[18];
    const float* bhh_b = (const float*)d_in[19];
    const float* W1    = (const float*)d_in[20];
    const float* b1    = (const float*)d_in[21];
    const float* W2    = (const float*)d_in[22];
    const float* b2    = (const float*)d_in[23];
    const float* W3    = (const float*)d_in[24];
    const float* b3    = (const float*)d_in[25];
    float* out = (float*)d_out;
    float* ws  = (float*)d_ws;

    float* te  = ws + OFF_TE;
    float* q   = ws + OFF_Q;
    float* k   = ws + OFF_K;
    float* ctx = ws + OFF_CTX;
    float* xs  = ws + OFF_XS;
    float* gif = ws + OFF_GIF;
    float* gib = ws + OFF_GIB;
    float* hf  = ws + OFF_HF;
    float* hb  = ws + OFF_HB;

    time_embed_kernel<<<NPOS*128/256, 256, 0, stream>>>(ts, w_lin, b_lin, w_per, b_per, te);
    gemm_kernel<0><<<dim3(NPOS/64, 1), 256, 0, stream>>>(te, Wq, bq, q, NPOS, 128, 128);
    gemm_kernel<0><<<dim3(NPOS/64, 1), 256, 0, stream>>>(te, Wk, bk, k, NPOS, 128, 128);
    attn_kernel<<<dim3(16, 4, 30), 256, 0, stream>>>(q, k, x, ctx);
    gemm_kernel<1><<<dim3(NPOS/64, 1), 256, 0, stream>>>(ctx, Wo, bo, xs, NPOS, 128, 512);
    gemm_kernel<0><<<dim3(NPOS/64, 3), 256, 0, stream>>>(xs, Wih_f, bih_f, gif, NPOS, 384, 128);
    gemm_kernel<2><<<dim3(NPOS/64, 3), 256, 0, stream>>>(xs, Wih_b, bih_b, gib, NPOS, 384, 128);
    gru_kernel<<<60, 512, 0, stream>>>(gif, gib, Whh_f, bhh_f, Whh_b, bhh_b, hf, hb);
    classifier_kernel<<<30, 128, 0, stream>>>(hf, hb, W1, b1, W2, b2, W3, b3, out);
}

// Round 9
// 1802.704 us; speedup vs baseline: 1.0254x; 1.0254x over previous
//
#include <hip/hip_runtime.h>
#include <math.h>

#define B_ 30
#define S_ 1024
#define D_ 128
#define ET_ 128
#define H_ 4
#define DK_ 32
#define NH_ 128
#define NPOS (B_*S_)   // 30720

// workspace float offsets (total 27,532,800 floats = 110.1 MB)
#define OFF_TE   0L
#define OFF_Q    3932160L
#define OFF_K    7864320L
#define OFF_CTX  11796480L
#define OFF_XS   0L          // aliases TE (dead after q/k proj)
#define OFF_GIF  3932160L    // aliases Q,K + head of CTX (dead after Wo proj)
#define OFF_GIB  15728640L   // aliases tail of CTX
#define OFF_HF   27525120L
#define OFF_HB   27528960L

typedef __attribute__((ext_vector_type(4))) short short4v;
typedef __attribute__((ext_vector_type(8))) short short8v;
typedef __attribute__((ext_vector_type(4))) float f32x4;

__device__ __forceinline__ short f2bf(float x) {
    unsigned u = __builtin_bit_cast(unsigned, x);
    unsigned r = (u + 0x7FFFu + ((u >> 16) & 1u)) >> 16;
    return (short)r;
}
__device__ __forceinline__ float bf2f(short s) {
    unsigned u = ((unsigned)(unsigned short)s) << 16;
    return __builtin_bit_cast(float, u);
}

__device__ __forceinline__ short8v pack8(const float4 a, const float4 b) {
    short8v v;
    v[0]=f2bf(a.x); v[1]=f2bf(a.y); v[2]=f2bf(a.z); v[3]=f2bf(a.w);
    v[4]=f2bf(b.x); v[5]=f2bf(b.y); v[6]=f2bf(b.z); v[7]=f2bf(b.w);
    return v;
}

// fast transcendentals (saturating-safe; GRU is a contraction so ~ulp-level
// per-step error cannot accumulate)
__device__ __forceinline__ float fsigmoid(float x) {
    return 1.f / (1.f + __expf(-x));
}
__device__ __forceinline__ float ftanh(float x) {
    return 1.f - 2.f / (__expf(2.f * x) + 1.f);
}

// ---------------------------------------------------------------- time embed
__global__ __launch_bounds__(256) void time_embed_kernel(
    const float* __restrict__ ts, const float* __restrict__ w_lin,
    const float* __restrict__ b_lin, const float* __restrict__ w_per,
    const float* __restrict__ b_per, float* __restrict__ te)
{
    const long idx = (long)blockIdx.x * 256 + threadIdx.x;  // NPOS*128 total
    const int pos = (int)(idx >> 7);
    const int j = (int)(idx & 127);
    const float tv = ts[pos];
    float v;
    if (j == 0) v = tv * w_lin[0] + b_lin[0];
    else        v = sinf(tv * w_per[j-1] + b_per[j-1]);
    te[idx] = v;
}

// ------------------------------------------------------- generic tiled GEMM
// C[m,n] = sum_f A[m,f]*W[n,f] + bias[n]  (+ bias2[n] for n<256 when FOLD)
// REMAP==0: plain. REMAP==1: write row m=b*S+s to xs row s*B+b (Wo proj).
// REMAP==2: read A row for logical m=s*B+b from (S-1-s)*B+b (backward gi).
// FOLD==1: bias2 = bhh, added for the r,z gate thirds (n<256) — folds the
// GRU's b_hh_{r,z} into gi exactly (saves registers/adds in the scan).
template<int REMAP, int FOLD>
__global__ __launch_bounds__(256) void gemm_kernel(
    const float* __restrict__ A, const float* __restrict__ W,
    const float* __restrict__ bias, const float* __restrict__ bias2,
    float* __restrict__ C, int M, int N, int K)
{
    __shared__ float Wsh[128][129];
    __shared__ float Ash[64][129];
    const int t = threadIdx.x;
    const int m0 = blockIdx.x * 64;
    const int n0 = blockIdx.y * 128;
    const int e  = t & 31;
    const int rb = (t >> 5) * 8;
    float acc[8][4];
#pragma unroll
    for (int i = 0; i < 8; ++i)
#pragma unroll
        for (int j = 0; j < 4; ++j) acc[i][j] = 0.f;

    for (int k0 = 0; k0 < K; k0 += 128) {
        const int f = t & 127;
        {
            const int e0 = t >> 7;
#pragma unroll 8
            for (int i = 0; i < 64; ++i) {
                const int n = e0 + 2*i;
                Wsh[n][f] = W[(long)(n0 + n) * K + k0 + f];
            }
            const int r0 = t >> 7;
#pragma unroll 8
            for (int i = 0; i < 32; ++i) {
                const int r = r0 + 2*i;
                const int m = m0 + r;
                long src;
                if (REMAP == 2) {
                    const int s = m / B_, bb = m % B_;
                    src = (long)((S_-1-s)*B_ + bb) * K;
                } else {
                    src = (long)m * K;
                }
                Ash[r][f] = A[src + k0 + f];
            }
        }
        __syncthreads();
#pragma unroll 2
        for (int ff = 0; ff < 128; ++ff) {
            float av[8];
#pragma unroll
            for (int rr = 0; rr < 8; ++rr) av[rr] = Ash[rb+rr][ff];
#pragma unroll
            for (int cg = 0; cg < 4; ++cg) {
                const float wv = Wsh[e + 32*cg][ff];
#pragma unroll
                for (int rr = 0; rr < 8; ++rr)
                    acc[rr][cg] = fmaf(av[rr], wv, acc[rr][cg]);
            }
        }
        __syncthreads();
    }
#pragma unroll
    for (int rr = 0; rr < 8; ++rr) {
#pragma unroll
        for (int cg = 0; cg < 4; ++cg) {
            const int n = n0 + e + 32*cg;
            const int m = m0 + rb + rr;
            float v = acc[rr][cg] + bias[n];
            if (FOLD) { if (n < 256) v += bias2[n]; }
            if (REMAP == 1) {
                const int bb = m / S_, s = m % S_;
                C[(long)(s*B_ + bb) * N + n] = v;
            } else {
                C[(long)m * N + n] = v;
            }
        }
    }
}

// ------------------------------------------------------------ fused attention
// MFMA flash attention, p-minus-one formulation (see round-3 notes).
#define SCALE_LOG2 (0.17677669529663687f * 1.4426950408889634f)

__global__ __launch_bounds__(256) void attn_kernel(
    const float* __restrict__ qbuf, const float* __restrict__ kbuf,
    const float* __restrict__ x, float* __restrict__ ctx)
{
    const int qt = blockIdx.x;   // 0..15
    const int h  = blockIdx.y;   // 0..3
    const int b  = blockIdx.z;   // 0..29
    const int q0 = qt * 64;
    const int t  = threadIdx.x;
    const int w    = t >> 6;
    const int lane = t & 63;
    const int l15  = lane & 15;
    const int lg   = lane >> 4;

    __shared__ short K_lds[64][40];     //  5120 B
    __shared__ short XT_lds[128][68];   // 17408 B, XT[d][key]
    __shared__ short P_lds[4][16][88];  // 11264 B, per-wave P' rows

    // Q fragment (scale*log2e folded in), held in registers
    short8v qf;
    {
        const float* qp = qbuf + ((long)(b*S_ + q0 + 16*w + l15))*ET_ + h*DK_ + 8*lg;
        float4 a = *(const float4*)qp;
        float4 c = *(const float4*)(qp + 4);
        a.x*=SCALE_LOG2; a.y*=SCALE_LOG2; a.z*=SCALE_LOG2; a.w*=SCALE_LOG2;
        c.x*=SCALE_LOG2; c.y*=SCALE_LOG2; c.z*=SCALE_LOG2; c.w*=SCALE_LOG2;
        qf = pack8(a, c);
    }

    short8v ones;
#pragma unroll
    for (int i = 0; i < 8; ++i) ones[i] = (short)0x3F80;  // bf16 1.0

    f32x4 acc[8];
#pragma unroll
    for (int i = 0; i < 8; ++i) acc[i] = (f32x4){0.f,0.f,0.f,0.f};
    float lsum = 0.f;
    const f32x4 zf = (f32x4){0.f,0.f,0.f,0.f};

    for (int kt = 0; kt < 16; ++kt) {
        const int key0 = kt * 64;
        // ---- stage K tile (64 keys x 32 dk, bf16, rows padded to 40)
        {
            const int key = t >> 2, c8 = (t & 3) * 8;
            const float* kp = kbuf + ((long)(b*S_ + key0 + key))*ET_ + h*DK_ + c8;
            float4 a = *(const float4*)kp;
            float4 c = *(const float4*)(kp + 4);
            *(short8v*)&K_lds[key][c8] = pack8(a, c);
        }
        // ---- stage X tile transposed: XT[d][key], key-pairs packed as u32
        {
            const int k2 = t & 31;       // key pair 2*k2, 2*k2+1
            const int dg = t >> 5;       // d range [16*dg, 16*dg+16)
            const float* xp0 = x + ((long)(b*S_ + key0 + 2*k2))*D_ + 16*dg;
            const float* xp1 = xp0 + D_;
            float v0[16], v1[16];
#pragma unroll
            for (int j4 = 0; j4 < 4; ++j4) {
                float4 a = ((const float4*)xp0)[j4];
                float4 c = ((const float4*)xp1)[j4];
                v0[4*j4+0]=a.x; v0[4*j4+1]=a.y; v0[4*j4+2]=a.z; v0[4*j4+3]=a.w;
                v1[4*j4+0]=c.x; v1[4*j4+1]=c.y; v1[4*j4+2]=c.z; v1[4*j4+3]=c.w;
            }
#pragma unroll
            for (int j = 0; j < 16; ++j) {
                unsigned u = (unsigned)(unsigned short)f2bf(v0[j])
                           | ((unsigned)(unsigned short)f2bf(v1[j]) << 16);
                *(unsigned*)&XT_lds[16*dg + j][2*k2] = u;
            }
        }
        __syncthreads();

        // ---- QK^T (swapped): sc[f] = K_frag(16 keys) x Q  -> S^T
        f32x4 sc[4];
#pragma unroll
        for (int f = 0; f < 4; ++f) {
            short8v kf = *(const short8v*)&K_lds[16*f + l15][8*lg];
            sc[f] = __builtin_amdgcn_mfma_f32_16x16x32_bf16(kf, qf, zf, 0, 0, 0);
        }

        // ---- p = exp2(s), store p' = p-1; accumulate row-sum of p
        float pw[4][4];
        float ps = 0.f;
#pragma unroll
        for (int f = 0; f < 4; ++f)
#pragma unroll
            for (int r = 0; r < 4; ++r) {
                const float p = exp2f(sc[f][r]);
                ps += p;
                pw[f][r] = p - 1.f;
            }
        ps += __shfl_xor(ps, 16);
        ps += __shfl_xor(ps, 32);
        lsum += ps;   // per-lane stat for q-row l15 (uniform across lg lanes)

        // ---- write P' to per-wave LDS as bf16 (pairs of adjacent keys)
#pragma unroll
        for (int f = 0; f < 4; ++f) {
            unsigned lo = (unsigned)(unsigned short)f2bf(pw[f][0])
                        | ((unsigned)(unsigned short)f2bf(pw[f][1]) << 16);
            unsigned hi = (unsigned)(unsigned short)f2bf(pw[f][2])
                        | ((unsigned)(unsigned short)f2bf(pw[f][3]) << 16);
            *(unsigned*)&P_lds[w][l15][16*f + 4*lg]     = lo;
            *(unsigned*)&P_lds[w][l15][16*f + 4*lg + 2] = hi;
        }

        // ---- PV: acc[dq] += (ones + P') x X   (two MFMAs per B-frag)
#pragma unroll
        for (int kb = 0; kb < 2; ++kb) {
            short8v pa = *(const short8v*)&P_lds[w][l15][32*kb + 8*lg];
#pragma unroll
            for (int dq = 0; dq < 8; ++dq) {
                const short* xr = &XT_lds[16*dq + l15][32*kb + 8*lg];
                short4v lo = *(const short4v*)xr;        // 8B-aligned ds_read_b64
                short4v hi = *(const short4v*)(xr + 4);
                short8v xb = __builtin_shufflevector(lo, hi, 0,1,2,3,4,5,6,7);
                acc[dq] = __builtin_amdgcn_mfma_f32_16x16x32_bf16(ones, xb, acc[dq], 0, 0, 0);
                acc[dq] = __builtin_amdgcn_mfma_f32_16x16x32_bf16(pa,   xb, acc[dq], 0, 0, 0);
            }
        }
        __syncthreads();
    }

    // ---- epilogue: normalize by 1/lsum, store ctx[b,s,h,d]
    const float inv = 1.f / lsum;
#pragma unroll
    for (int r = 0; r < 4; ++r) {
        const float ir = __shfl(inv, (lane & 48) | (4*lg + r));
        const long base = ((long)(b*S_ + q0 + 16*w + 4*lg + r)*H_ + h)*D_ + l15;
#pragma unroll
        for (int d = 0; d < 8; ++d)
            ctx[base + (long)d*16] = acc[d][r] * ir;
    }
}

// ----------------------------------------------------------------- GRU scan
// 60 blocks: dir x batch. 512 threads = 8 waves; wave w owns h rows
// [16w,16w+16), A-tiles = gate rows {16w, 128+16w, 256+16w}.
// R8 post-mortem: the allocator's budget is empirically 128 VGPR for this
// kernel regardless of launch_bounds; R7/R8's hi/lo WEIGHT split (96 regs)
// + per-lane gate state (~190 live) spilled every step. Fix: move the
// precision split to the B side, exploiting that B's 16 columns were fully
// redundant: cols 0-7 carry h_hi = bf16(h), cols 8-15 carry
// h_lo = bf16(h - h_hi). One single-bf16 weight fragment set (48 regs)
// then computes W*h_hi AND W*h_lo in the SAME MFMA (12 MFMAs/step/wave,
// half of R7); gh = D[col] + D[col^8] via one __shfl_xor(8) + add.
// Error becomes (W-W_bf16)*h instead of W*(h-h_bf16) — same magnitude as
// the R6 version that passed at 4.9e-4. bhh_{r,z} folded into gi by the
// GEMM (FOLD=1); only bhh_n kept (inside r*(...)). Live regs ~116 < 128.
__global__ __launch_bounds__(512, 2) void gru_kernel(
    const float* __restrict__ gi_f, const float* __restrict__ gi_b,
    const float* __restrict__ Whh_f, const float* __restrict__ bhh_f,
    const float* __restrict__ Whh_b, const float* __restrict__ bhh_b,
    float* __restrict__ hf, float* __restrict__ hb)
{
    const int bid = blockIdx.x;
    const int dir = bid / B_;
    const int b   = bid % B_;
    const float* gi  = dir ? gi_b  : gi_f;
    const float* Whh = dir ? Whh_b : Whh_f;
    const float* bhh = dir ? bhh_b : bhh_f;
    float* hout      = dir ? hb    : hf;
    const int t    = threadIdx.x;        // 0..511
    const int w    = t >> 6;             // wave 0..7 -> h rows [16w,16w+16)
    const int lane = t & 63;
    const int l15  = lane & 15;
    const int lg   = lane >> 4;
    const int sel  = l15 >> 3;           // 0: h_hi columns, 1: h_lo columns
    const int j0   = 16*w + 4*lg;        // this lane's 4 h indices

    // Whh fragments: tile rt covers gate rows 128*rt + [16w, 16w+16)
    short8v wa[3][4];
#pragma unroll
    for (int rt = 0; rt < 3; ++rt) {
        const int row = 128*rt + 16*w + l15;
#pragma unroll
        for (int kf = 0; kf < 4; ++kf) {
            const float* wp = Whh + (long)row*128 + 32*kf + 8*lg;
            float4 a = *(const float4*)wp;
            float4 c = *(const float4*)(wp + 4);
            wa[rt][kf] = pack8(a, c);
        }
    }

    // n-gate hidden bias (r,z biases folded into gi by the GEMM)
    const f32x4 bn = *(const f32x4*)(bhh + 256 + j0);

    __shared__ __align__(16) short hbf[2][2][128];   // [buf][hi/lo][128]
    if (t < 128) { hbf[0][0][t] = 0; hbf[0][1][t] = 0; }
    __syncthreads();

    f32x4 hcur = (f32x4){0.f,0.f,0.f,0.f};           // f32 recurrence state

    // gi for step 0
    const float* g0 = gi + (long)b * 384;
    f32x4 gr = *(const f32x4*)(g0 + j0);
    f32x4 gz = *(const f32x4*)(g0 + 128 + j0);
    f32x4 gn = *(const f32x4*)(g0 + 256 + j0);

    for (int s = 0; s < S_; ++s) {
        const int cur = s & 1, nxt = cur ^ 1;

        // B-fragments: hi-half lanes read h_hi, lo-half lanes read h_lo
        short8v hfrag[4];
#pragma unroll
        for (int kf = 0; kf < 4; ++kf)
            hfrag[kf] = *(const short8v*)&hbf[cur][sel][32*kf + 8*lg];

        // prefetch next step's gi (latency hides under the MFMA phase)
        f32x4 ngr = gr, ngz = gz, ngn = gn;
        if (s + 1 < S_) {
            const float* g = gi + ((long)(s+1)*B_ + b) * 384;
            ngr = *(const f32x4*)(g + j0);
            ngz = *(const f32x4*)(g + 128 + j0);
            ngn = *(const f32x4*)(g + 256 + j0);
        }

        // gh tiles: cols 0-7 = W*h_hi, cols 8-15 = W*h_lo; combine via xor-8
        f32x4 gh0, gh1, gh2;
#define GH_TILE(rt, OUT) { \
        f32x4 a_ = (f32x4){0.f,0.f,0.f,0.f}; \
        _Pragma("unroll") \
        for (int kf = 0; kf < 4; ++kf) \
            a_ = __builtin_amdgcn_mfma_f32_16x16x32_bf16(wa[rt][kf], hfrag[kf], a_, 0,0,0); \
        _Pragma("unroll") \
        for (int r = 0; r < 4; ++r) a_[r] += __shfl_xor(a_[r], 8); \
        OUT = a_; }
        GH_TILE(0, gh0)
        GH_TILE(1, gh1)
        GH_TILE(2, gh2)
#undef GH_TILE

        // gate math for j0..j0+3 (replicated across the 8 lanes per (lg,sel))
#pragma unroll
        for (int r = 0; r < 4; ++r) {
            const float rr = fsigmoid(gr[r] + gh0[r]);          // bhh_r in gi
            const float zz = fsigmoid(gz[r] + gh1[r]);          // bhh_z in gi
            const float nn = ftanh (gn[r] + rr * (gh2[r] + bn[r]));
            hcur[r] = (1.f - zz)*nn + zz*hcur[r];
        }

        // publish new h: one lane per (lg,sel) writes its 4 rows (hi or lo)
        if ((l15 & 7) == 0) {
            short4v hv;
#pragma unroll
            for (int r = 0; r < 4; ++r) {
                const short hi = f2bf(hcur[r]);
                hv[r] = sel ? f2bf(hcur[r] - bf2f(hi)) : hi;
            }
            *(short4v*)&hbf[nxt][sel][j0] = hv;
        }
        gr = ngr; gz = ngz; gn = ngn;
        __syncthreads();
    }

    if (l15 == 0)
        *(f32x4*)&hout[(long)b*128 + j0] = hcur;
}

// -------------------------------------------------------------- classifier
__global__ __launch_bounds__(128) void classifier_kernel(
    const float* __restrict__ hf, const float* __restrict__ hb,
    const float* __restrict__ W1, const float* __restrict__ b1,
    const float* __restrict__ W2, const float* __restrict__ b2,
    const float* __restrict__ W3, const float* __restrict__ b3,
    float* __restrict__ out)
{
    const int b = blockIdx.x;
    const int t = threadIdx.x;
    __shared__ float cin[256], a1[128], a2[64];
    cin[t]       = hf[(long)b*128 + t];
    cin[128 + t] = hb[(long)b*128 + t];
    __syncthreads();
    {
        float a = b1[t];
        for (int i = 0; i < 256; ++i) a = fmaf(W1[(long)t*256 + i], cin[i], a);
        a1[t] = a;
    }
    __syncthreads();
    if (t < 64) {
        float a = b2[t];
        for (int i = 0; i < 128; ++i) a = fmaf(W2[(long)t*128 + i], a1[i], a);
        a2[t] = a;
    }
    __syncthreads();
    if (t < 6) {
        float a = b3[t];
        for (int i = 0; i < 64; ++i) a = fmaf(W3[(long)t*64 + i], a2[i], a);
        out[(long)b*6 + t] = a;
    }
}

// ------------------------------------------------------------------- launch
extern "C" void kernel_launch(void* const* d_in, const int* in_sizes, int n_in,
                              void* d_out, int out_size, void* d_ws, size_t ws_size,
                              hipStream_t stream)
{
    const float* x     = (const float*)d_in[0];
    const float* ts    = (const float*)d_in[1];
    const float* w_lin = (const float*)d_in[2];
    const float* b_lin = (const float*)d_in[3];
    const float* w_per = (const float*)d_in[4];
    const float* b_per = (const float*)d_in[5];
    const float* Wq    = (const float*)d_in[6];
    const float* bq    = (const float*)d_in[7];
    const float* Wk    = (const float*)d_in[8];
    const float* bk    = (const float*)d_in[9];
    const float* Wo    = (const float*)d_in[10];
    const float* bo    = (const float*)d_in[11];
    const float* Wih_f = (const float*)d_in[12];
    const float* Whh_f = (const float*)d_in[13];
    const float* bih_f = (const float*)d_in[14];
    const float* bhh_f = (const float*)d_in[15];
    const float* Wih_b = (const float*)d_in[16];
    const float* Whh_b = (const float*)d_in[17];
    const float* bih_b = (const float*)d_in[18];
    const float* bhh_b = (const float*)d_in[19];
    const float* W1    = (const float*)d_in[20];
    const float* b1    = (const float*)d_in[21];
    const float* W2    = (const float*)d_in[22];
    const float* b2    = (const float*)d_in[23];
    const float* W3    = (const float*)d_in[24];
    const float* b3    = (const float*)d_in[25];
    float* out = (float*)d_out;
    float* ws  = (float*)d_ws;

    float* te  = ws + OFF_TE;
    float* q   = ws + OFF_Q;
    float* k   = ws + OFF_K;
    float* ctx = ws + OFF_CTX;
    float* xs  = ws + OFF_XS;
    float* gif = ws + OFF_GIF;
    float* gib = ws + OFF_GIB;
    float* hf  = ws + OFF_HF;
    float* hb  = ws + OFF_HB;

    time_embed_kernel<<<NPOS*128/256, 256, 0, stream>>>(ts, w_lin, b_lin, w_per, b_per, te);
    gemm_kernel<0,0><<<dim3(NPOS/64, 1), 256, 0, stream>>>(te, Wq, bq, nullptr, q, NPOS, 128, 128);
    gemm_kernel<0,0><<<dim3(NPOS/64, 1), 256, 0, stream>>>(te, Wk, bk, nullptr, k, NPOS, 128, 128);
    attn_kernel<<<dim3(16, 4, 30), 256, 0, stream>>>(q, k, x, ctx);
    gemm_kernel<1,0><<<dim3(NPOS/64, 1), 256, 0, stream>>>(ctx, Wo, bo, nullptr, xs, NPOS, 128, 512);
    gemm_kernel<0,1><<<dim3(NPOS/64, 3), 256, 0, stream>>>(xs, Wih_f, bih_f, bhh_f, gif, NPOS, 384, 128);
    gemm_kernel<2,1><<<dim3(NPOS/64, 3), 256, 0, stream>>>(xs, Wih_b, bih_b, bhh_b, gib, NPOS, 384, 128);
    gru_kernel<<<60, 512, 0, stream>>>(gif, gib, Whh_f, bhh_f, Whh_b, bhh_b, hf, hb);
    classifier_kernel<<<30, 128, 0, stream>>>(hf, hb, W1, b1, W2, b2, W3, b3, out);
}

// Round 11
// 1101.268 us; speedup vs baseline: 1.6785x; 1.6369x over previous
//
#include <hip/hip_runtime.h>
#include <math.h>

#define B_ 30
#define S_ 1024
#define D_ 128
#define ET_ 128
#define H_ 4
#define DK_ 32
#define NH_ 128
#define NPOS (B_*S_)   // 30720

// workspace float offsets (total 27,532,800 floats = 110.1 MB)
#define OFF_TE   0L
#define OFF_Q    3932160L
#define OFF_K    7864320L
#define OFF_CTX  11796480L
#define OFF_XS   0L          // aliases TE (dead after q/k proj)
#define OFF_GIF  3932160L    // aliases Q,K + head of CTX (dead after Wo proj)
#define OFF_GIB  15728640L   // aliases tail of CTX
#define OFF_HF   27525120L
#define OFF_HB   27528960L

typedef __attribute__((ext_vector_type(4))) short short4v;
typedef __attribute__((ext_vector_type(8))) short short8v;
typedef __attribute__((ext_vector_type(4))) float f32x4;

__device__ __forceinline__ short f2bf(float x) {
    unsigned u = __builtin_bit_cast(unsigned, x);
    unsigned r = (u + 0x7FFFu + ((u >> 16) & 1u)) >> 16;
    return (short)r;
}
__device__ __forceinline__ float bf2f(short s) {
    unsigned u = ((unsigned)(unsigned short)s) << 16;
    return __builtin_bit_cast(float, u);
}

__device__ __forceinline__ short8v pack8(const float4 a, const float4 b) {
    short8v v;
    v[0]=f2bf(a.x); v[1]=f2bf(a.y); v[2]=f2bf(a.z); v[3]=f2bf(a.w);
    v[4]=f2bf(b.x); v[5]=f2bf(b.y); v[6]=f2bf(b.z); v[7]=f2bf(b.w);
    return v;
}

// split a float8 (two float4) into bf16 hi + bf16 residual lo
__device__ __forceinline__ void pack_hilo(const float4 a, const float4 b,
                                          short8v& hi, short8v& lo) {
    float v[8] = {a.x,a.y,a.z,a.w,b.x,b.y,b.z,b.w};
#pragma unroll
    for (int e = 0; e < 8; ++e) {
        hi[e] = f2bf(v[e]);
        lo[e] = f2bf(v[e] - bf2f(hi[e]));
    }
}

// fast transcendentals (saturating-safe; GRU is a contraction)
__device__ __forceinline__ float fsigmoid(float x) {
    return 1.f / (1.f + __expf(-x));
}
__device__ __forceinline__ float ftanh(float x) {
    return 1.f - 2.f / (__expf(2.f * x) + 1.f);
}

// ---------------------------------------------------------------- time embed
__global__ __launch_bounds__(256) void time_embed_kernel(
    const float* __restrict__ ts, const float* __restrict__ w_lin,
    const float* __restrict__ b_lin, const float* __restrict__ w_per,
    const float* __restrict__ b_per, float* __restrict__ te)
{
    const long idx = (long)blockIdx.x * 256 + threadIdx.x;  // NPOS*128 total
    const int pos = (int)(idx >> 7);
    const int j = (int)(idx & 127);
    const float tv = ts[pos];
    float v;
    if (j == 0) v = tv * w_lin[0] + b_lin[0];
    else        v = sinf(tv * w_per[j-1] + b_per[j-1]);
    te[idx] = v;
}

// --------------------------------------------------- MFMA split-precision GEMM
// C[m,n] = sum_k A[m,k]*W[n,k] + bias[n].  A,W split to bf16 hi + residual lo;
// A*W ~= Ahi*Whi + Alo*Whi + Ahi*Wlo (error ~1e-5 rel, fp32-like).
// Block: 256 thr = 4 waves; tile 64(M) x 128(N); K staged 64/iter.
// Fragment layouts HW-verified by attn/gru: A-op row=l15 k=8lg+e;
// B-op col=l15 k=8lg+e; D row=4lg+reg col=l15.
// REMAP==0 plain; ==1 write m=b*S+s to row s*B+b (Wo proj); ==2 read A row
// for m=s*B+b from (S-1-s)*B+b (backward gi). FOLD==1 adds bias2[n] for n<256.
// R10 post-mortem: W-staging only wrote cols c32+0..15 (q<2) leaving
// c32+16..31 of W_hi/W_lo uninitialized -> NaN. q must run 0..3.
template<int REMAP, int FOLD>
__global__ __launch_bounds__(256) void gemm_mfma_kernel(
    const float* __restrict__ A, const float* __restrict__ W,
    const float* __restrict__ bias, const float* __restrict__ bias2,
    float* __restrict__ C, int M, int N, int K)
{
    __shared__ short A_hi[64][72], A_lo[64][72];     // 18.4 KB
    __shared__ short W_hi[128][72], W_lo[128][72];   // 36.9 KB
    const int t = threadIdx.x;
    const int m0 = blockIdx.x * 64;
    const int n0 = blockIdx.y * 128;
    const int w = t >> 6, lane = t & 63;
    const int l15 = lane & 15, lg = lane >> 4;

    f32x4 acc[8];
#pragma unroll
    for (int i = 0; i < 8; ++i) acc[i] = (f32x4){0.f,0.f,0.f,0.f};

    for (int k0 = 0; k0 < K; k0 += 64) {
        {   // stage A tile 64x64: thread t -> row t>>2, cols (t&3)*16..+15
            const int r = t >> 2, c16 = (t & 3) * 16;
            const int m = m0 + r;
            long src;
            if (REMAP == 2) {
                const int s = m / B_, bb = m % B_;
                src = (long)((S_-1-s)*B_ + bb) * K;
            } else {
                src = (long)m * K;
            }
            const float4* ap = (const float4*)(A + src + k0 + c16);
            short8v h0, l0, h1, l1;
            pack_hilo(ap[0], ap[1], h0, l0);
            pack_hilo(ap[2], ap[3], h1, l1);
            *(short8v*)&A_hi[r][c16]     = h0;
            *(short8v*)&A_hi[r][c16 + 8] = h1;
            *(short8v*)&A_lo[r][c16]     = l0;
            *(short8v*)&A_lo[r][c16 + 8] = l1;
        }
        {   // stage W tile 128x64: thread t -> row t>>1, cols (t&1)*32..+31
            const int n = t >> 1, c32 = (t & 1) * 32;
            const float4* wp = (const float4*)(W + (long)(n0 + n) * K + k0 + c32);
#pragma unroll
            for (int q = 0; q < 4; ++q) {      // 4 x 8 floats = all 32 cols
                short8v h, l;
                pack_hilo(wp[2*q], wp[2*q + 1], h, l);
                *(short8v*)&W_hi[n][c32 + 8*q] = h;
                *(short8v*)&W_lo[n][c32 + 8*q] = l;
            }
        }
        __syncthreads();
#pragma unroll
        for (int kk = 0; kk < 64; kk += 32) {
            short8v ah = *(const short8v*)&A_hi[16*w + l15][kk + 8*lg];
            short8v al = *(const short8v*)&A_lo[16*w + l15][kk + 8*lg];
#pragma unroll
            for (int nf = 0; nf < 8; ++nf) {
                short8v wh = *(const short8v*)&W_hi[16*nf + l15][kk + 8*lg];
                short8v wl = *(const short8v*)&W_lo[16*nf + l15][kk + 8*lg];
                acc[nf] = __builtin_amdgcn_mfma_f32_16x16x32_bf16(ah, wh, acc[nf], 0,0,0);
                acc[nf] = __builtin_amdgcn_mfma_f32_16x16x32_bf16(al, wh, acc[nf], 0,0,0);
                acc[nf] = __builtin_amdgcn_mfma_f32_16x16x32_bf16(ah, wl, acc[nf], 0,0,0);
            }
        }
        __syncthreads();
    }

#pragma unroll
    for (int nf = 0; nf < 8; ++nf) {
#pragma unroll
        for (int r = 0; r < 4; ++r) {
            const int n = n0 + 16*nf + l15;
            const int m = m0 + 16*w + 4*lg + r;
            float v = acc[nf][r] + bias[n];
            if (FOLD) { if (n < 256) v += bias2[n]; }
            if (REMAP == 1) {
                const int bb = m / S_, s = m % S_;
                C[(long)(s*B_ + bb) * N + n] = v;
            } else {
                C[(long)m * N + n] = v;
            }
        }
    }
}

// ------------------------------------------------------------ fused attention
// MFMA flash attention, p-minus-one formulation (see round-3 notes).
#define SCALE_LOG2 (0.17677669529663687f * 1.4426950408889634f)

__global__ __launch_bounds__(256) void attn_kernel(
    const float* __restrict__ qbuf, const float* __restrict__ kbuf,
    const float* __restrict__ x, float* __restrict__ ctx)
{
    const int qt = blockIdx.x;   // 0..15
    const int h  = blockIdx.y;   // 0..3
    const int b  = blockIdx.z;   // 0..29
    const int q0 = qt * 64;
    const int t  = threadIdx.x;
    const int w    = t >> 6;
    const int lane = t & 63;
    const int l15  = lane & 15;
    const int lg   = lane >> 4;

    __shared__ short K_lds[64][40];     //  5120 B
    __shared__ short XT_lds[128][68];   // 17408 B, XT[d][key]
    __shared__ short P_lds[4][16][88];  // 11264 B, per-wave P' rows

    short8v qf;
    {
        const float* qp = qbuf + ((long)(b*S_ + q0 + 16*w + l15))*ET_ + h*DK_ + 8*lg;
        float4 a = *(const float4*)qp;
        float4 c = *(const float4*)(qp + 4);
        a.x*=SCALE_LOG2; a.y*=SCALE_LOG2; a.z*=SCALE_LOG2; a.w*=SCALE_LOG2;
        c.x*=SCALE_LOG2; c.y*=SCALE_LOG2; c.z*=SCALE_LOG2; c.w*=SCALE_LOG2;
        qf = pack8(a, c);
    }

    short8v ones;
#pragma unroll
    for (int i = 0; i < 8; ++i) ones[i] = (short)0x3F80;  // bf16 1.0

    f32x4 acc[8];
#pragma unroll
    for (int i = 0; i < 8; ++i) acc[i] = (f32x4){0.f,0.f,0.f,0.f};
    float lsum = 0.f;
    const f32x4 zf = (f32x4){0.f,0.f,0.f,0.f};

    for (int kt = 0; kt < 16; ++kt) {
        const int key0 = kt * 64;
        {
            const int key = t >> 2, c8 = (t & 3) * 8;
            const float* kp = kbuf + ((long)(b*S_ + key0 + key))*ET_ + h*DK_ + c8;
            float4 a = *(const float4*)kp;
            float4 c = *(const float4*)(kp + 4);
            *(short8v*)&K_lds[key][c8] = pack8(a, c);
        }
        {
            const int k2 = t & 31;
            const int dg = t >> 5;
            const float* xp0 = x + ((long)(b*S_ + key0 + 2*k2))*D_ + 16*dg;
            const float* xp1 = xp0 + D_;
            float v0[16], v1[16];
#pragma unroll
            for (int j4 = 0; j4 < 4; ++j4) {
                float4 a = ((const float4*)xp0)[j4];
                float4 c = ((const float4*)xp1)[j4];
                v0[4*j4+0]=a.x; v0[4*j4+1]=a.y; v0[4*j4+2]=a.z; v0[4*j4+3]=a.w;
                v1[4*j4+0]=c.x; v1[4*j4+1]=c.y; v1[4*j4+2]=c.z; v1[4*j4+3]=c.w;
            }
#pragma unroll
            for (int j = 0; j < 16; ++j) {
                unsigned u = (unsigned)(unsigned short)f2bf(v0[j])
                           | ((unsigned)(unsigned short)f2bf(v1[j]) << 16);
                *(unsigned*)&XT_lds[16*dg + j][2*k2] = u;
            }
        }
        __syncthreads();

        f32x4 sc[4];
#pragma unroll
        for (int f = 0; f < 4; ++f) {
            short8v kf = *(const short8v*)&K_lds[16*f + l15][8*lg];
            sc[f] = __builtin_amdgcn_mfma_f32_16x16x32_bf16(kf, qf, zf, 0, 0, 0);
        }

        float pw[4][4];
        float ps = 0.f;
#pragma unroll
        for (int f = 0; f < 4; ++f)
#pragma unroll
            for (int r = 0; r < 4; ++r) {
                const float p = exp2f(sc[f][r]);
                ps += p;
                pw[f][r] = p - 1.f;
            }
        ps += __shfl_xor(ps, 16);
        ps += __shfl_xor(ps, 32);
        lsum += ps;

#pragma unroll
        for (int f = 0; f < 4; ++f) {
            unsigned lo = (unsigned)(unsigned short)f2bf(pw[f][0])
                        | ((unsigned)(unsigned short)f2bf(pw[f][1]) << 16);
            unsigned hi = (unsigned)(unsigned short)f2bf(pw[f][2])
                        | ((unsigned)(unsigned short)f2bf(pw[f][3]) << 16);
            *(unsigned*)&P_lds[w][l15][16*f + 4*lg]     = lo;
            *(unsigned*)&P_lds[w][l15][16*f + 4*lg + 2] = hi;
        }

#pragma unroll
        for (int kb = 0; kb < 2; ++kb) {
            short8v pa = *(const short8v*)&P_lds[w][l15][32*kb + 8*lg];
#pragma unroll
            for (int dq = 0; dq < 8; ++dq) {
                const short* xr = &XT_lds[16*dq + l15][32*kb + 8*lg];
                short4v lo = *(const short4v*)xr;
                short4v hi = *(const short4v*)(xr + 4);
                short8v xb = __builtin_shufflevector(lo, hi, 0,1,2,3,4,5,6,7);
                acc[dq] = __builtin_amdgcn_mfma_f32_16x16x32_bf16(ones, xb, acc[dq], 0, 0, 0);
                acc[dq] = __builtin_amdgcn_mfma_f32_16x16x32_bf16(pa,   xb, acc[dq], 0, 0, 0);
            }
        }
        __syncthreads();
    }

    const float inv = 1.f / lsum;
#pragma unroll
    for (int r = 0; r < 4; ++r) {
        const float ir = __shfl(inv, (lane & 48) | (4*lg + r));
        const long base = ((long)(b*S_ + q0 + 16*w + 4*lg + r)*H_ + h)*D_ + l15;
#pragma unroll
        for (int d = 0; d < 8; ++d)
            ctx[base + (long)d*16] = acc[d][r] * ir;
    }
}

// ----------------------------------------------------------------- GRU scan
// R6 two-barrier structure + B-side hi/lo split: B cols 0-7 carry h_hi,
// cols 8-15 h_lo, so ONE bf16 weight fragment set (48 VGPR, 12 MFMAs/step/
// wave) computes both products; lanes l15==0 / l15==8 write ghs_hi / ghs_lo;
// the 128 gate threads sum them (no ds_bpermute on the critical path).
// Gate math + gi prefetch confined to t<128. bhh_{r,z} folded into gi by
// the GEMM; bhh_n applied here.
__global__ __launch_bounds__(512, 1) void gru_kernel(
    const float* __restrict__ gi_f, const float* __restrict__ gi_b,
    const float* __restrict__ Whh_f, const float* __restrict__ bhh_f,
    const float* __restrict__ Whh_b, const float* __restrict__ bhh_b,
    float* __restrict__ hf, float* __restrict__ hb)
{
    const int bid = blockIdx.x;
    const int dir = bid / B_;
    const int b   = bid % B_;
    const float* gi  = dir ? gi_b  : gi_f;
    const float* Whh = dir ? Whh_b : Whh_f;
    const float* bhh = dir ? bhh_b : bhh_f;
    float* hout      = dir ? hb    : hf;
    const int t    = threadIdx.x;        // 0..511
    const int w    = t >> 6;             // wave 0..7
    const int lane = t & 63;
    const int l15  = lane & 15;
    const int lg   = lane >> 4;
    const int sel  = l15 >> 3;           // 0: h_hi cols, 1: h_lo cols

    // Whh fragments (single bf16): tile rt = gate rows (3w+rt)*16 + l15
    short8v wa[3][4];
#pragma unroll
    for (int rt = 0; rt < 3; ++rt) {
        const int row = (3*w + rt)*16 + l15;
#pragma unroll
        for (int kf = 0; kf < 4; ++kf) {
            const float* wp = Whh + (long)row*128 + 32*kf + 8*lg;
            float4 a = *(const float4*)wp;
            float4 c = *(const float4*)(wp + 4);
            wa[rt][kf] = pack8(a, c);
        }
    }

    __shared__ __align__(16) float ghs_hi[384], ghs_lo[384];
    __shared__ __align__(16) short hbf[2][2][128];   // [buf][hi/lo][128]

    float hreg = 0.f;
    float bnj = 0.f;
    float gir = 0.f, giz = 0.f, gin = 0.f;
    if (t < 128) {
        hbf[0][0][t] = 0; hbf[0][1][t] = 0;
        bnj = bhh[256 + t];
        const float* g = gi + (long)b * 384;
        gir = g[t]; giz = g[128+t]; gin = g[256+t];
    }
    __syncthreads();

    for (int s = 0; s < S_; ++s) {
        const int cur = s & 1, nxt = cur ^ 1;

        // B-fragments: hi-col lanes read h_hi, lo-col lanes read h_lo
        short8v hfrag[4];
#pragma unroll
        for (int kf = 0; kf < 4; ++kf)
            hfrag[kf] = *(const short8v*)&hbf[cur][sel][32*kf + 8*lg];

        // gh tiles on the matrix pipe; col 0 = W*h_hi, col 8 = W*h_lo
#pragma unroll
        for (int rt = 0; rt < 3; ++rt) {
            f32x4 cacc = (f32x4){0.f,0.f,0.f,0.f};
#pragma unroll
            for (int kf = 0; kf < 4; ++kf)
                cacc = __builtin_amdgcn_mfma_f32_16x16x32_bf16(wa[rt][kf], hfrag[kf], cacc, 0,0,0);
            if (l15 == 0)      *(f32x4*)&ghs_hi[(3*w + rt)*16 + 4*lg] = cacc;
            else if (l15 == 8) *(f32x4*)&ghs_lo[(3*w + rt)*16 + 4*lg] = cacc;
        }

        // prefetch next step's gi (t<128 only, scalar — R6 style)
        float ngir = 0.f, ngiz = 0.f, ngin = 0.f;
        if (t < 128 && s + 1 < S_) {
            const float* g = gi + ((long)(s+1)*B_ + b) * 384;
            ngir = g[t]; ngiz = g[128+t]; ngin = g[256+t];
        }
        __syncthreads();
        if (t < 128) {
            const float ghr = ghs_hi[t]     + ghs_lo[t];
            const float ghz = ghs_hi[128+t] + ghs_lo[128+t];
            const float ghn = ghs_hi[256+t] + ghs_lo[256+t];
            const float r = fsigmoid(gir + ghr);            // bhh_r in gi
            const float z = fsigmoid(giz + ghz);            // bhh_z in gi
            const float n = ftanh (gin + r * (ghn + bnj));
            hreg = (1.f - z)*n + z*hreg;
            const short hi = f2bf(hreg);
            hbf[nxt][0][t] = hi;
            hbf[nxt][1][t] = f2bf(hreg - bf2f(hi));
            gir = ngir; giz = ngiz; gin = ngin;
        }
        __syncthreads();
    }
    if (t < 128) hout[(long)b*128 + t] = hreg;
}

// -------------------------------------------------------------- classifier
__global__ __launch_bounds__(128) void classifier_kernel(
    const float* __restrict__ hf, const float* __restrict__ hb,
    const float* __restrict__ W1, const float* __restrict__ b1,
    const float* __restrict__ W2, const float* __restrict__ b2,
    const float* __restrict__ W3, const float* __restrict__ b3,
    float* __restrict__ out)
{
    const int b = blockIdx.x;
    const int t = threadIdx.x;
    __shared__ float cin[256], a1[128], a2[64];
    cin[t]       = hf[(long)b*128 + t];
    cin[128 + t] = hb[(long)b*128 + t];
    __syncthreads();
    {
        float a = b1[t];
        for (int i = 0; i < 256; ++i) a = fmaf(W1[(long)t*256 + i], cin[i], a);
        a1[t] = a;
    }
    __syncthreads();
    if (t < 64) {
        float a = b2[t];
        for (int i = 0; i < 128; ++i) a = fmaf(W2[(long)t*128 + i], a1[i], a);
        a2[t] = a;
    }
    __syncthreads();
    if (t < 6) {
        float a = b3[t];
        for (int i = 0; i < 64; ++i) a = fmaf(W3[(long)t*64 + i], a2[i], a);
        out[(long)b*6 + t] = a;
    }
}

// ------------------------------------------------------------------- launch
extern "C" void kernel_launch(void* const* d_in, const int* in_sizes, int n_in,
                              void* d_out, int out_size, void* d_ws, size_t ws_size,
                              hipStream_t stream)
{
    const float* x     = (const float*)d_in[0];
    const float* ts    = (const float*)d_in[1];
    const float* w_lin = (const float*)d_in[2];
    const float* b_lin = (const float*)d_in[3];
    const float* w_per = (const float*)d_in[4];
    const float* b_per = (const float*)d_in[5];
    const float* Wq    = (const float*)d_in[6];
    const float* bq    = (const float*)d_in[7];
    const float* Wk    = (const float*)d_in[8];
    const float* bk    = (const float*)d_in[9];
    const float* Wo    = (const float*)d_in[10];
    const float* bo    = (const float*)d_in[11];
    const float* Wih_f = (const float*)d_in[12];
    const float* Whh_f = (const float*)d_in[13];
    const float* bih_f = (const float*)d_in[14];
    const float* bhh_f = (const float*)d_in[15];
    const float* Wih_b = (const float*)d_in[16];
    const float* Whh_b = (const float*)d_in[17];
    const float* bih_b = (const float*)d_in[18];
    const float* bhh_b = (const float*)d_in[19];
    const float* W1    = (const float*)d_in[20];
    const float* b1    = (const float*)d_in[21];
    const float* W2    = (const float*)d_in[22];
    const float* b2    = (const float*)d_in[23];
    const float* W3    = (const float*)d_in[24];
    const float* b3    = (const float*)d_in[25];
    float* out = (float*)d_out;
    float* ws  = (float*)d_ws;

    float* te  = ws + OFF_TE;
    float* q   = ws + OFF_Q;
    float* k   = ws + OFF_K;
    float* ctx = ws + OFF_CTX;
    float* xs  = ws + OFF_XS;
    float* gif = ws + OFF_GIF;
    float* gib = ws + OFF_GIB;
    float* hf  = ws + OFF_HF;
    float* hb  = ws + OFF_HB;

    time_embed_kernel<<<NPOS*128/256, 256, 0, stream>>>(ts, w_lin, b_lin, w_per, b_per, te);
    gemm_mfma_kernel<0,0><<<dim3(NPOS/64, 1), 256, 0, stream>>>(te, Wq, bq, nullptr, q, NPOS, 128, 128);
    gemm_mfma_kernel<0,0><<<dim3(NPOS/64, 1), 256, 0, stream>>>(te, Wk, bk, nullptr, k, NPOS, 128, 128);
    attn_kernel<<<dim3(16, 4, 30), 256, 0, stream>>>(q, k, x, ctx);
    gemm_mfma_kernel<1,0><<<dim3(NPOS/64, 1), 256, 0, stream>>>(ctx, Wo, bo, nullptr, xs, NPOS, 128, 512);
    gemm_mfma_kernel<0,1><<<dim3(NPOS/64, 3), 256, 0, stream>>>(xs, Wih_f, bih_f, bhh_f, gif, NPOS, 384, 128);
    gemm_mfma_kernel<2,1><<<dim3(NPOS/64, 3), 256, 0, stream>>>(xs, Wih_b, bih_b, bhh_b, gib, NPOS, 384, 128);
    gru_kernel<<<60, 512, 0, stream>>>(gif, gib, Whh_f, bhh_f, Whh_b, bhh_b, hf, hb);
    classifier_kernel<<<30, 128, 0, stream>>>(hf, hb, W1, b1, W2, b2, W3, b3, out);
}

// Round 12
// 1007.399 us; speedup vs baseline: 1.8349x; 1.0932x over previous
//
#include <hip/hip_runtime.h>
#include <math.h>

#define B_ 30
#define S_ 1024
#define D_ 128
#define ET_ 128
#define H_ 4
#define DK_ 32
#define NH_ 128
#define NPOS (B_*S_)   // 30720

// workspace float offsets (total 27,532,800 floats = 110.1 MB)
#define OFF_TE   0L
#define OFF_Q    3932160L
#define OFF_K    7864320L
#define OFF_CTX  11796480L
#define OFF_XS   0L          // aliases TE (dead after q/k proj)
#define OFF_GIF  3932160L    // aliases Q,K + head of CTX (dead after Wo proj)
#define OFF_GIB  15728640L   // aliases tail of CTX
#define OFF_HF   27525120L
#define OFF_HB   27528960L

typedef __attribute__((ext_vector_type(4))) short short4v;
typedef __attribute__((ext_vector_type(8))) short short8v;
typedef __attribute__((ext_vector_type(4))) float f32x4;

__device__ __forceinline__ short f2bf(float x) {
    unsigned u = __builtin_bit_cast(unsigned, x);
    unsigned r = (u + 0x7FFFu + ((u >> 16) & 1u)) >> 16;
    return (short)r;
}
__device__ __forceinline__ float bf2f(short s) {
    unsigned u = ((unsigned)(unsigned short)s) << 16;
    return __builtin_bit_cast(float, u);
}

__device__ __forceinline__ short8v pack8(const float4 a, const float4 b) {
    short8v v;
    v[0]=f2bf(a.x); v[1]=f2bf(a.y); v[2]=f2bf(a.z); v[3]=f2bf(a.w);
    v[4]=f2bf(b.x); v[5]=f2bf(b.y); v[6]=f2bf(b.z); v[7]=f2bf(b.w);
    return v;
}

// split a float8 (two float4) into bf16 hi + bf16 residual lo
__device__ __forceinline__ void pack_hilo(const float4 a, const float4 b,
                                          short8v& hi, short8v& lo) {
    float v[8] = {a.x,a.y,a.z,a.w,b.x,b.y,b.z,b.w};
#pragma unroll
    for (int e = 0; e < 8; ++e) {
        hi[e] = f2bf(v[e]);
        lo[e] = f2bf(v[e] - bf2f(hi[e]));
    }
}

// fast transcendentals (saturating-safe; GRU is a contraction)
__device__ __forceinline__ float fsigmoid(float x) {
    return 1.f / (1.f + __expf(-x));
}
__device__ __forceinline__ float ftanh(float x) {
    return 1.f - 2.f / (__expf(2.f * x) + 1.f);
}

// LDS-only block sync: orders LDS ops (lgkmcnt(0)) but does NOT drain vmcnt,
// so in-flight global prefetch loads survive across the barrier (the
// __syncthreads() vmcnt(0) drain was serializing ~full HBM latency into
// every GRU step). sched_barrier fences per rule #18.
__device__ __forceinline__ void sync_lds() {
    asm volatile("s_waitcnt lgkmcnt(0)" ::: "memory");
    __builtin_amdgcn_sched_barrier(0);
    __builtin_amdgcn_s_barrier();
    __builtin_amdgcn_sched_barrier(0);
}

// ---------------------------------------------------------------- time embed
__global__ __launch_bounds__(256) void time_embed_kernel(
    const float* __restrict__ ts, const float* __restrict__ w_lin,
    const float* __restrict__ b_lin, const float* __restrict__ w_per,
    const float* __restrict__ b_per, float* __restrict__ te)
{
    const long idx = (long)blockIdx.x * 256 + threadIdx.x;  // NPOS*128 total
    const int pos = (int)(idx >> 7);
    const int j = (int)(idx & 127);
    const float tv = ts[pos];
    float v;
    if (j == 0) v = tv * w_lin[0] + b_lin[0];
    else        v = sinf(tv * w_per[j-1] + b_per[j-1]);
    te[idx] = v;
}

// --------------------------------------------------- MFMA split-precision GEMM
// (unchanged from R11, which passed at absmax 1.2e-4)
template<int REMAP, int FOLD>
__global__ __launch_bounds__(256) void gemm_mfma_kernel(
    const float* __restrict__ A, const float* __restrict__ W,
    const float* __restrict__ bias, const float* __restrict__ bias2,
    float* __restrict__ C, int M, int N, int K)
{
    __shared__ short A_hi[64][72], A_lo[64][72];     // 18.4 KB
    __shared__ short W_hi[128][72], W_lo[128][72];   // 36.9 KB
    const int t = threadIdx.x;
    const int m0 = blockIdx.x * 64;
    const int n0 = blockIdx.y * 128;
    const int w = t >> 6, lane = t & 63;
    const int l15 = lane & 15, lg = lane >> 4;

    f32x4 acc[8];
#pragma unroll
    for (int i = 0; i < 8; ++i) acc[i] = (f32x4){0.f,0.f,0.f,0.f};

    for (int k0 = 0; k0 < K; k0 += 64) {
        {   // stage A tile 64x64
            const int r = t >> 2, c16 = (t & 3) * 16;
            const int m = m0 + r;
            long src;
            if (REMAP == 2) {
                const int s = m / B_, bb = m % B_;
                src = (long)((S_-1-s)*B_ + bb) * K;
            } else {
                src = (long)m * K;
            }
            const float4* ap = (const float4*)(A + src + k0 + c16);
            short8v h0, l0, h1, l1;
            pack_hilo(ap[0], ap[1], h0, l0);
            pack_hilo(ap[2], ap[3], h1, l1);
            *(short8v*)&A_hi[r][c16]     = h0;
            *(short8v*)&A_hi[r][c16 + 8] = h1;
            *(short8v*)&A_lo[r][c16]     = l0;
            *(short8v*)&A_lo[r][c16 + 8] = l1;
        }
        {   // stage W tile 128x64 (q runs 0..3 — R10 NaN fix)
            const int n = t >> 1, c32 = (t & 1) * 32;
            const float4* wp = (const float4*)(W + (long)(n0 + n) * K + k0 + c32);
#pragma unroll
            for (int q = 0; q < 4; ++q) {
                short8v h, l;
                pack_hilo(wp[2*q], wp[2*q + 1], h, l);
                *(short8v*)&W_hi[n][c32 + 8*q] = h;
                *(short8v*)&W_lo[n][c32 + 8*q] = l;
            }
        }
        __syncthreads();
#pragma unroll
        for (int kk = 0; kk < 64; kk += 32) {
            short8v ah = *(const short8v*)&A_hi[16*w + l15][kk + 8*lg];
            short8v al = *(const short8v*)&A_lo[16*w + l15][kk + 8*lg];
#pragma unroll
            for (int nf = 0; nf < 8; ++nf) {
                short8v wh = *(const short8v*)&W_hi[16*nf + l15][kk + 8*lg];
                short8v wl = *(const short8v*)&W_lo[16*nf + l15][kk + 8*lg];
                acc[nf] = __builtin_amdgcn_mfma_f32_16x16x32_bf16(ah, wh, acc[nf], 0,0,0);
                acc[nf] = __builtin_amdgcn_mfma_f32_16x16x32_bf16(al, wh, acc[nf], 0,0,0);
                acc[nf] = __builtin_amdgcn_mfma_f32_16x16x32_bf16(ah, wl, acc[nf], 0,0,0);
            }
        }
        __syncthreads();
    }

#pragma unroll
    for (int nf = 0; nf < 8; ++nf) {
#pragma unroll
        for (int r = 0; r < 4; ++r) {
            const int n = n0 + 16*nf + l15;
            const int m = m0 + 16*w + 4*lg + r;
            float v = acc[nf][r] + bias[n];
            if (FOLD) { if (n < 256) v += bias2[n]; }
            if (REMAP == 1) {
                const int bb = m / S_, s = m % S_;
                C[(long)(s*B_ + bb) * N + n] = v;
            } else {
                C[(long)m * N + n] = v;
            }
        }
    }
}

// ------------------------------------------------------------ fused attention
// MFMA flash attention, p-minus-one formulation (unchanged from R11).
#define SCALE_LOG2 (0.17677669529663687f * 1.4426950408889634f)

__global__ __launch_bounds__(256) void attn_kernel(
    const float* __restrict__ qbuf, const float* __restrict__ kbuf,
    const float* __restrict__ x, float* __restrict__ ctx)
{
    const int qt = blockIdx.x;   // 0..15
    const int h  = blockIdx.y;   // 0..3
    const int b  = blockIdx.z;   // 0..29
    const int q0 = qt * 64;
    const int t  = threadIdx.x;
    const int w    = t >> 6;
    const int lane = t & 63;
    const int l15  = lane & 15;
    const int lg   = lane >> 4;

    __shared__ short K_lds[64][40];     //  5120 B
    __shared__ short XT_lds[128][68];   // 17408 B, XT[d][key]
    __shared__ short P_lds[4][16][88];  // 11264 B, per-wave P' rows

    short8v qf;
    {
        const float* qp = qbuf + ((long)(b*S_ + q0 + 16*w + l15))*ET_ + h*DK_ + 8*lg;
        float4 a = *(const float4*)qp;
        float4 c = *(const float4*)(qp + 4);
        a.x*=SCALE_LOG2; a.y*=SCALE_LOG2; a.z*=SCALE_LOG2; a.w*=SCALE_LOG2;
        c.x*=SCALE_LOG2; c.y*=SCALE_LOG2; c.z*=SCALE_LOG2; c.w*=SCALE_LOG2;
        qf = pack8(a, c);
    }

    short8v ones;
#pragma unroll
    for (int i = 0; i < 8; ++i) ones[i] = (short)0x3F80;  // bf16 1.0

    f32x4 acc[8];
#pragma unroll
    for (int i = 0; i < 8; ++i) acc[i] = (f32x4){0.f,0.f,0.f,0.f};
    float lsum = 0.f;
    const f32x4 zf = (f32x4){0.f,0.f,0.f,0.f};

    for (int kt = 0; kt < 16; ++kt) {
        const int key0 = kt * 64;
        {
            const int key = t >> 2, c8 = (t & 3) * 8;
            const float* kp = kbuf + ((long)(b*S_ + key0 + key))*ET_ + h*DK_ + c8;
            float4 a = *(const float4*)kp;
            float4 c = *(const float4*)(kp + 4);
            *(short8v*)&K_lds[key][c8] = pack8(a, c);
        }
        {
            const int k2 = t & 31;
            const int dg = t >> 5;
            const float* xp0 = x + ((long)(b*S_ + key0 + 2*k2))*D_ + 16*dg;
            const float* xp1 = xp0 + D_;
            float v0[16], v1[16];
#pragma unroll
            for (int j4 = 0; j4 < 4; ++j4) {
                float4 a = ((const float4*)xp0)[j4];
                float4 c = ((const float4*)xp1)[j4];
                v0[4*j4+0]=a.x; v0[4*j4+1]=a.y; v0[4*j4+2]=a.z; v0[4*j4+3]=a.w;
                v1[4*j4+0]=c.x; v1[4*j4+1]=c.y; v1[4*j4+2]=c.z; v1[4*j4+3]=c.w;
            }
#pragma unroll
            for (int j = 0; j < 16; ++j) {
                unsigned u = (unsigned)(unsigned short)f2bf(v0[j])
                           | ((unsigned)(unsigned short)f2bf(v1[j]) << 16);
                *(unsigned*)&XT_lds[16*dg + j][2*k2] = u;
            }
        }
        __syncthreads();

        f32x4 sc[4];
#pragma unroll
        for (int f = 0; f < 4; ++f) {
            short8v kf = *(const short8v*)&K_lds[16*f + l15][8*lg];
            sc[f] = __builtin_amdgcn_mfma_f32_16x16x32_bf16(kf, qf, zf, 0, 0, 0);
        }

        float pw[4][4];
        float ps = 0.f;
#pragma unroll
        for (int f = 0; f < 4; ++f)
#pragma unroll
            for (int r = 0; r < 4; ++r) {
                const float p = exp2f(sc[f][r]);
                ps += p;
                pw[f][r] = p - 1.f;
            }
        ps += __shfl_xor(ps, 16);
        ps += __shfl_xor(ps, 32);
        lsum += ps;

#pragma unroll
        for (int f = 0; f < 4; ++f) {
            unsigned lo = (unsigned)(unsigned short)f2bf(pw[f][0])
                        | ((unsigned)(unsigned short)f2bf(pw[f][1]) << 16);
            unsigned hi = (unsigned)(unsigned short)f2bf(pw[f][2])
                        | ((unsigned)(unsigned short)f2bf(pw[f][3]) << 16);
            *(unsigned*)&P_lds[w][l15][16*f + 4*lg]     = lo;
            *(unsigned*)&P_lds[w][l15][16*f + 4*lg + 2] = hi;
        }

#pragma unroll
        for (int kb = 0; kb < 2; ++kb) {
            short8v pa = *(const short8v*)&P_lds[w][l15][32*kb + 8*lg];
#pragma unroll
            for (int dq = 0; dq < 8; ++dq) {
                const short* xr = &XT_lds[16*dq + l15][32*kb + 8*lg];
                short4v lo = *(const short4v*)xr;
                short4v hi = *(const short4v*)(xr + 4);
                short8v xb = __builtin_shufflevector(lo, hi, 0,1,2,3,4,5,6,7);
                acc[dq] = __builtin_amdgcn_mfma_f32_16x16x32_bf16(ones, xb, acc[dq], 0, 0, 0);
                acc[dq] = __builtin_amdgcn_mfma_f32_16x16x32_bf16(pa,   xb, acc[dq], 0, 0, 0);
            }
        }
        __syncthreads();
    }

    const float inv = 1.f / lsum;
#pragma unroll
    for (int r = 0; r < 4; ++r) {
        const float ir = __shfl(inv, (lane & 48) | (4*lg + r));
        const long base = ((long)(b*S_ + q0 + 16*w + 4*lg + r)*H_ + h)*D_ + l15;
#pragma unroll
        for (int d = 0; d < 8; ++d)
            ctx[base + (long)d*16] = acc[d][r] * ir;
    }
}

// ----------------------------------------------------------------- GRU scan
// R11 structure + three latency fixes:
// (1) sync_lds(): raw s_barrier + lgkmcnt(0)-only — __syncthreads()'s
//     vmcnt(0) drain was serializing the per-step gi global prefetch
//     (~400-900 cyc) into every step.
// (2) 2-step-unrolled gi prefetch with parity register sets (no reg copies,
//     so the compiler's vmcnt wait lands at first USE ~a full step after
//     issue -> load latency fully hidden under the MFMA phase).
// (3) bank-depad: ghs[800] (lo at +400 words = +16 banks) and
//     hbf[2][2][160] (hi/lo 80 words apart = +16 banks) -> the hi/lo
//     halves hit disjoint bank halves (was 7.86M conflicts = 128 cyc/step).
__global__ __launch_bounds__(512, 1) void gru_kernel(
    const float* __restrict__ gi_f, const float* __restrict__ gi_b,
    const float* __restrict__ Whh_f, const float* __restrict__ bhh_f,
    const float* __restrict__ Whh_b, const float* __restrict__ bhh_b,
    float* __restrict__ hf, float* __restrict__ hb)
{
    const int bid = blockIdx.x;
    const int dir = bid / B_;
    const int b   = bid % B_;
    const float* gi  = dir ? gi_b  : gi_f;
    const float* Whh = dir ? Whh_b : Whh_f;
    const float* bhh = dir ? bhh_b : bhh_f;
    float* hout      = dir ? hb    : hf;
    const int t    = threadIdx.x;        // 0..511
    const int w    = t >> 6;             // wave 0..7
    const int lane = t & 63;
    const int l15  = lane & 15;
    const int lg   = lane >> 4;
    const int sel  = l15 >> 3;           // 0: h_hi cols, 1: h_lo cols

    // Whh fragments (single bf16): tile rt = gate rows (3w+rt)*16 + l15
    short8v wa[3][4];
#pragma unroll
    for (int rt = 0; rt < 3; ++rt) {
        const int row = (3*w + rt)*16 + l15;
#pragma unroll
        for (int kf = 0; kf < 4; ++kf) {
            const float* wp = Whh + (long)row*128 + 32*kf + 8*lg;
            float4 a = *(const float4*)wp;
            float4 c = *(const float4*)(wp + 4);
            wa[rt][kf] = pack8(a, c);
        }
    }

    __shared__ __align__(16) float ghs[800];        // hi rows at [0..383], lo at [400..783]
    __shared__ __align__(16) short hbf[2][2][160];  // [buf][hi/lo][pad 160]

    float hreg = 0.f;
    float bnj = 0.f;
    float gar = 0.f, gaz = 0.f, gan = 0.f;   // parity set A (even steps)
    float gbr = 0.f, gbz = 0.f, gbn = 0.f;   // parity set B (odd steps)
    if (t < 128) {
        hbf[0][0][t] = 0; hbf[0][1][t] = 0;
        bnj = bhh[256 + t];
        const float* g = gi + (long)b * 384;
        gar = g[t]; gaz = g[128+t]; gan = g[256+t];
    }
    __syncthreads();   // one-time full sync (drains the s=0 load; fine)

#define GRU_STEP(CUR, GR, GZ, GN)                                              \
    {                                                                          \
        short8v hfrag[4];                                                      \
        _Pragma("unroll")                                                      \
        for (int kf = 0; kf < 4; ++kf)                                         \
            hfrag[kf] = *(const short8v*)&hbf[CUR][sel][32*kf + 8*lg];         \
        _Pragma("unroll")                                                      \
        for (int rt = 0; rt < 3; ++rt) {                                       \
            f32x4 cacc = (f32x4){0.f,0.f,0.f,0.f};                             \
            _Pragma("unroll")                                                  \
            for (int kf = 0; kf < 4; ++kf)                                     \
                cacc = __builtin_amdgcn_mfma_f32_16x16x32_bf16(                \
                    wa[rt][kf], hfrag[kf], cacc, 0,0,0);                       \
            if (l15 == 0)                                                      \
                *(f32x4*)&ghs[(3*w + rt)*16 + 4*lg] = cacc;                    \
            else if (l15 == 8)                                                 \
                *(f32x4*)&ghs[400 + (3*w + rt)*16 + 4*lg] = cacc;              \
        }                                                                      \
        sync_lds();                                                            \
        if (t < 128) {                                                         \
            const float ghr = ghs[t]       + ghs[400+t];                       \
            const float ghz = ghs[128+t]   + ghs[528+t];                       \
            const float ghn = ghs[256+t]   + ghs[656+t];                       \
            const float r = fsigmoid(GR + ghr);                                \
            const float z = fsigmoid(GZ + ghz);                                \
            const float n = ftanh (GN + r * (ghn + bnj));                      \
            hreg = (1.f - z)*n + z*hreg;                                       \
            const short hi = f2bf(hreg);                                       \
            hbf[(CUR)^1][0][t] = hi;                                           \
            hbf[(CUR)^1][1][t] = f2bf(hreg - bf2f(hi));                        \
        }                                                                      \
        sync_lds();                                                            \
    }

    for (int s = 0; s < S_; s += 2) {
        // even step s: uses set A; issue set-B load (for s+1) FIRST so its
        // latency hides under this step's MFMA phase + barrier
        if (t < 128) {
            const float* g = gi + ((long)(s+1)*B_ + b) * 384;
            gbr = g[t]; gbz = g[128+t]; gbn = g[256+t];
        }
        GRU_STEP(0, gar, gaz, gan)
        // odd step s+1: uses set B; issue set-A load (for s+2)
        if (t < 128 && s + 2 < S_) {
            const float* g = gi + ((long)(s+2)*B_ + b) * 384;
            gar = g[t]; gaz = g[128+t]; gan = g[256+t];
        }
        GRU_STEP(1, gbr, gbz, gbn)
    }
#undef GRU_STEP

    if (t < 128) hout[(long)b*128 + t] = hreg;
}

// -------------------------------------------------------------- classifier
__global__ __launch_bounds__(128) void classifier_kernel(
    const float* __restrict__ hf, const float* __restrict__ hb,
    const float* __restrict__ W1, const float* __restrict__ b1,
    const float* __restrict__ W2, const float* __restrict__ b2,
    const float* __restrict__ W3, const float* __restrict__ b3,
    float* __restrict__ out)
{
    const int b = blockIdx.x;
    const int t = threadIdx.x;
    __shared__ float cin[256], a1[128], a2[64];
    cin[t]       = hf[(long)b*128 + t];
    cin[128 + t] = hb[(long)b*128 + t];
    __syncthreads();
    {
        float a = b1[t];
        for (int i = 0; i < 256; ++i) a = fmaf(W1[(long)t*256 + i], cin[i], a);
        a1[t] = a;
    }
    __syncthreads();
    if (t < 64) {
        float a = b2[t];
        for (int i = 0; i < 128; ++i) a = fmaf(W2[(long)t*128 + i], a1[i], a);
        a2[t] = a;
    }
    __syncthreads();
    if (t < 6) {
        float a = b3[t];
        for (int i = 0; i < 64; ++i) a = fmaf(W3[(long)t*64 + i], a2[i], a);
        out[(long)b*6 + t] = a;
    }
}

// ------------------------------------------------------------------- launch
extern "C" void kernel_launch(void* const* d_in, const int* in_sizes, int n_in,
                              void* d_out, int out_size, void* d_ws, size_t ws_size,
                              hipStream_t stream)
{
    const float* x     = (const float*)d_in[0];
    const float* ts    = (const float*)d_in[1];
    const float* w_lin = (const float*)d_in[2];
    const float* b_lin = (const float*)d_in[3];
    const float* w_per = (const float*)d_in[4];
    const float* b_per = (const float*)d_in[5];
    const float* Wq    = (const float*)d_in[6];
    const float* bq    = (const float*)d_in[7];
    const float* Wk    = (const float*)d_in[8];
    const float* bk    = (const float*)d_in[9];
    const float* Wo    = (const float*)d_in[10];
    const float* bo    = (const float*)d_in[11];
    const float* Wih_f = (const float*)d_in[12];
    const float* Whh_f = (const float*)d_in[13];
    const float* bih_f = (const float*)d_in[14];
    const float* bhh_f = (const float*)d_in[15];
    const float* Wih_b = (const float*)d_in[16];
    const float* Whh_b = (const float*)d_in[17];
    const float* bih_b = (const float*)d_in[18];
    const float* bhh_b = (const float*)d_in[19];
    const float* W1    = (const float*)d_in[20];
    const float* b1    = (const float*)d_in[21];
    const float* W2    = (const float*)d_in[22];
    const float* b2    = (const float*)d_in[23];
    const float* W3    = (const float*)d_in[24];
    const float* b3    = (const float*)d_in[25];
    float* out = (float*)d_out;
    float* ws  = (float*)d_ws;

    float* te  = ws + OFF_TE;
    float* q   = ws + OFF_Q;
    float* k   = ws + OFF_K;
    float* ctx = ws + OFF_CTX;
    float* xs  = ws + OFF_XS;
    float* gif = ws + OFF_GIF;
    float* gib = ws + OFF_GIB;
    float* hf  = ws + OFF_HF;
    float* hb  = ws + OFF_HB;

    time_embed_kernel<<<NPOS*128/256, 256, 0, stream>>>(ts, w_lin, b_lin, w_per, b_per, te);
    gemm_mfma_kernel<0,0><<<dim3(NPOS/64, 1), 256, 0, stream>>>(te, Wq, bq, nullptr, q, NPOS, 128, 128);
    gemm_mfma_kernel<0,0><<<dim3(NPOS/64, 1), 256, 0, stream>>>(te, Wk, bk, nullptr, k, NPOS, 128, 128);
    attn_kernel<<<dim3(16, 4, 30), 256, 0, stream>>>(q, k, x, ctx);
    gemm_mfma_kernel<1,0><<<dim3(NPOS/64, 1), 256, 0, stream>>>(ctx, Wo, bo, nullptr, xs, NPOS, 128, 512);
    gemm_mfma_kernel<0,1><<<dim3(NPOS/64, 3), 256, 0, stream>>>(xs, Wih_f, bih_f, bhh_f, gif, NPOS, 384, 128);
    gemm_mfma_kernel<2,1><<<dim3(NPOS/64, 3), 256, 0, stream>>>(xs, Wih_b, bih_b, bhh_b, gib, NPOS, 384, 128);
    gru_kernel<<<60, 512, 0, stream>>>(gif, gib, Whh_f, bhh_f, Whh_b, bhh_b, hf, hb);
    classifier_kernel<<<30, 128, 0, stream>>>(hf, hb, W1, b1, W2, b2, W3, b3, out);
}